// Round 1
// baseline (194.777 us; speedup 1.0000x reference)
//
#include <hip/hip_runtime.h>
#include <hip/hip_bf16.h>

#define L_SEQ 2048
#define D_HEAD 64
#define NHEADS 64   // B*H = 4*16
#define L2E 1.44269504088896340736f
#define QSCALE (0.125f * L2E)   // 1/sqrt(64) * log2(e), folded into Q staging

typedef __attribute__((ext_vector_type(8))) __bf16 bf16x8;
typedef __attribute__((ext_vector_type(4))) float f32x4;

// Byte offset into a [rows][64] bf16 tile (128B rows), XOR-swizzled so that
// column-slice b128 reads across rows hit distinct bank groups (G4 fix).
__device__ __forceinline__ int swz(int row, int col) {
    int off = (row << 7) | (col << 1);
    return off ^ ((row & 7) << 4);
}

// Stage a [rows][64] fp32 tile (row stride srcStride elements) into swizzled
// bf16 LDS. 256 threads; each thread does rows/16 iterations of
// float4 global load -> 4x cvt -> 8B ds_write.
__device__ __forceinline__ void stage_tile(char* lds, const float* src, int rows,
                                           int srcStride, int t, float scale) {
    int r0 = t >> 4;
    int c4 = (t & 15) << 2;
    for (int rr = 0; rr < rows; rr += 16) {
        int row = r0 + rr;
        float4 v = *reinterpret_cast<const float4*>(src + (size_t)row * srcStride + c4);
        union { __bf16 h[4]; unsigned long long u; } pk;
        pk.h[0] = (__bf16)(v.x * scale);
        pk.h[1] = (__bf16)(v.y * scale);
        pk.h[2] = (__bf16)(v.z * scale);
        pk.h[3] = (__bf16)(v.w * scale);
        *reinterpret_cast<unsigned long long*>(lds + swz(row, c4)) = pk.u;
    }
}

__device__ __forceinline__ bf16x8 read_frag(const char* lds, int row, int col) {
    return *reinterpret_cast<const bf16x8*>(lds + swz(row, col));
}

// -------- Pass 1: invl[bh][q] = 1 / sum_k exp2(QSCALE * (Q.K)) --------------
__global__ __launch_bounds__(256, 2) void attn_pass1(const float* __restrict__ Q,
                                                     const float* __restrict__ K,
                                                     float* __restrict__ invl) {
    __shared__ __align__(16) char ldsQ[64 * 128];
    __shared__ __align__(16) char ldsK[128 * 128];
    __shared__ float red[4][64];

    int bh = blockIdx.x >> 5;            // 32 q-tiles per head
    int q0 = (blockIdx.x & 31) << 6;
    const float* Qh = Q + (size_t)bh * L_SEQ * D_HEAD + (size_t)q0 * D_HEAD;
    const float* Kh = K + (size_t)bh * L_SEQ * D_HEAD;

    int t = threadIdx.x;
    int lane = t & 63;
    int w = t >> 6;          // wave 0..3 owns k-cols [w*32, w*32+32)
    int lg = lane >> 4;
    int ln = lane & 15;

    stage_tile(ldsQ, Qh, 64, D_HEAD, t, QSCALE);

    float lsum[4][4];
    for (int qf = 0; qf < 4; ++qf)
        for (int r = 0; r < 4; ++r) lsum[qf][r] = 0.f;

    for (int k0 = 0; k0 < L_SEQ; k0 += 128) {
        __syncthreads();
        stage_tile(ldsK, Kh + (size_t)k0 * D_HEAD, 128, D_HEAD, t, 1.0f);
        __syncthreads();

        f32x4 s[4][2];
        for (int qf = 0; qf < 4; ++qf)
            for (int kf = 0; kf < 2; ++kf) s[qf][kf] = {0.f, 0.f, 0.f, 0.f};

        for (int dc = 0; dc < 2; ++dc) {
            bf16x8 bfr[2];
            for (int kf = 0; kf < 2; ++kf)
                bfr[kf] = read_frag(ldsK, w * 32 + kf * 16 + ln, dc * 32 + lg * 8);
            for (int qf = 0; qf < 4; ++qf) {
                bf16x8 afr = read_frag(ldsQ, qf * 16 + ln, dc * 32 + lg * 8);
                for (int kf = 0; kf < 2; ++kf)
                    s[qf][kf] = __builtin_amdgcn_mfma_f32_16x16x32_bf16(
                        afr, bfr[kf], s[qf][kf], 0, 0, 0);
            }
        }
        for (int qf = 0; qf < 4; ++qf)
            for (int kf = 0; kf < 2; ++kf)
                for (int r = 0; r < 4; ++r)
                    lsum[qf][r] += __builtin_amdgcn_exp2f(s[qf][kf][r]);
    }

    // row-reduce across the 16 lanes of each quarter-wave group
    for (int qf = 0; qf < 4; ++qf)
        for (int r = 0; r < 4; ++r) {
            float v = lsum[qf][r];
            v += __shfl_xor(v, 1);
            v += __shfl_xor(v, 2);
            v += __shfl_xor(v, 4);
            v += __shfl_xor(v, 8);
            lsum[qf][r] = v;
        }
    if (ln == 0) {
        for (int qf = 0; qf < 4; ++qf)
            for (int r = 0; r < 4; ++r)
                red[w][qf * 16 + lg * 4 + r] = lsum[qf][r];
    }
    __syncthreads();
    if (t < 64) {
        float ssum = red[0][t] + red[1][t] + red[2][t] + red[3][t];
        invl[(size_t)bh * L_SEQ + q0 + t] = 1.0f / ssum;
    }
}

// -------- Pass 2: Out[d, k-tile] = sum_q V[d,q] * exp2(s[q,k]) * invl[q] ----
__global__ __launch_bounds__(256, 2) void attn_pass2(const float* __restrict__ Q,
                                                     const float* __restrict__ K,
                                                     const float* __restrict__ V,
                                                     const float* __restrict__ invl,
                                                     float* __restrict__ out) {
    __shared__ __align__(16) char ldsK[128 * 128];  // K[k][d]   (k-tile rows)
    __shared__ __align__(16) char ldsQ[64 * 128];   // Q[q][d]
    __shared__ __align__(16) char ldsV[64 * 128];   // V[d][q]
    __shared__ __align__(16) char ldsP[128 * 128];  // P^T[k][q]

    int bh = blockIdx.x >> 4;            // 16 k-tiles of 128 per head
    int k0 = (blockIdx.x & 15) << 7;
    const float* Qh = Q + (size_t)bh * L_SEQ * D_HEAD;
    const float* Kh = K + (size_t)bh * L_SEQ * D_HEAD + (size_t)k0 * D_HEAD;
    const float* Vh = V + (size_t)bh * D_HEAD * L_SEQ;
    const float* il = invl + (size_t)bh * L_SEQ;
    float* Oh = out + (size_t)bh * D_HEAD * L_SEQ;

    int t = threadIdx.x;
    int lane = t & 63;
    int w = t >> 6;          // wave owns out k-cols [w*32, w*32+32)
    int lg = lane >> 4;
    int ln = lane & 15;

    stage_tile(ldsK, Kh, 128, D_HEAD, t, 1.0f);

    f32x4 acc[4][2];
    for (int df = 0; df < 4; ++df)
        for (int kf = 0; kf < 2; ++kf) acc[df][kf] = {0.f, 0.f, 0.f, 0.f};

    for (int q0 = 0; q0 < L_SEQ; q0 += 64) {
        __syncthreads();   // previous iter's MFMA2 done before overwriting Q/V
        stage_tile(ldsQ, Qh + (size_t)q0 * D_HEAD, 64, D_HEAD, t, QSCALE);
        stage_tile(ldsV, Vh + q0, 64, L_SEQ, t, 1.0f);
        __syncthreads();

        // S-tile: s[q, k] for this wave's 32 k-cols (bit-identical to pass 1)
        f32x4 s[4][2];
        for (int qf = 0; qf < 4; ++qf)
            for (int kf = 0; kf < 2; ++kf) s[qf][kf] = {0.f, 0.f, 0.f, 0.f};

        for (int dc = 0; dc < 2; ++dc) {
            bf16x8 bfr[2];
            for (int kf = 0; kf < 2; ++kf)
                bfr[kf] = read_frag(ldsK, w * 32 + kf * 16 + ln, dc * 32 + lg * 8);
            for (int qf = 0; qf < 4; ++qf) {
                bf16x8 afr = read_frag(ldsQ, qf * 16 + ln, dc * 32 + lg * 8);
                for (int kf = 0; kf < 2; ++kf)
                    s[qf][kf] = __builtin_amdgcn_mfma_f32_16x16x32_bf16(
                        afr, bfr[kf], s[qf][kf], 0, 0, 0);
            }
        }

        // P^T[k][q] = bf16( exp2(s) * invl[q] ), packed 4 q per lane per write
        for (int qf = 0; qf < 4; ++qf) {
            float4 il4 = *reinterpret_cast<const float4*>(il + q0 + qf * 16 + lg * 4);
            for (int kf = 0; kf < 2; ++kf) {
                union { __bf16 h[4]; unsigned long long u; } pk;
                pk.h[0] = (__bf16)(__builtin_amdgcn_exp2f(s[qf][kf][0]) * il4.x);
                pk.h[1] = (__bf16)(__builtin_amdgcn_exp2f(s[qf][kf][1]) * il4.y);
                pk.h[2] = (__bf16)(__builtin_amdgcn_exp2f(s[qf][kf][2]) * il4.z);
                pk.h[3] = (__bf16)(__builtin_amdgcn_exp2f(s[qf][kf][3]) * il4.w);
                int krow = w * 32 + kf * 16 + ln;
                int qcol = qf * 16 + lg * 4;
                *reinterpret_cast<unsigned long long*>(ldsP + swz(krow, qcol)) = pk.u;
            }
        }
        __syncthreads();

        // Out[d, k] += V[d, q-tile] @ P[q-tile, k]
        for (int qc = 0; qc < 2; ++qc) {
            bf16x8 pfr[2];
            for (int kf = 0; kf < 2; ++kf)
                pfr[kf] = read_frag(ldsP, w * 32 + kf * 16 + ln, qc * 32 + lg * 8);
            for (int df = 0; df < 4; ++df) {
                bf16x8 vfr = read_frag(ldsV, df * 16 + ln, qc * 32 + lg * 8);
                for (int kf = 0; kf < 2; ++kf)
                    acc[df][kf] = __builtin_amdgcn_mfma_f32_16x16x32_bf16(
                        vfr, pfr[kf], acc[df][kf], 0, 0, 0);
            }
        }
    }

    for (int df = 0; df < 4; ++df)
        for (int kf = 0; kf < 2; ++kf)
            for (int r = 0; r < 4; ++r) {
                int d = df * 16 + lg * 4 + r;
                int k = k0 + w * 32 + kf * 16 + ln;
                Oh[(size_t)d * L_SEQ + k] = acc[df][kf][r];
            }
}

extern "C" void kernel_launch(void* const* d_in, const int* in_sizes, int n_in,
                              void* d_out, int out_size, void* d_ws, size_t ws_size,
                              hipStream_t stream) {
    const float* Q = (const float*)d_in[0];
    const float* K = (const float*)d_in[1];
    const float* V = (const float*)d_in[2];
    float* invl = (float*)d_ws;          // NHEADS * L_SEQ floats = 512 KB
    float* out = (float*)d_out;

    attn_pass1<<<dim3(NHEADS * (L_SEQ / 64)), dim3(256), 0, stream>>>(Q, K, invl);
    attn_pass2<<<dim3(NHEADS * (L_SEQ / 128)), dim3(256), 0, stream>>>(Q, K, V, invl, out);
}